// Round 7
// baseline (78.149 us; speedup 1.0000x reference)
//
#include <hip/hip_runtime.h>
#include <stdint.h>

#define D_DIM 128
#define NROW 8192          // 2B
#define L2EPS 1e-12f
// MFMA output = sim * 10/ln2 (exp2 arg): data pre-scaled by sqrt((10/ln2)/16),
// MX scales A=2^4 (131), B=2^0 (127).
#define SCALE_PRE 0.9495707f
#define LN2 0.6931471805599453f

typedef __attribute__((ext_vector_type(4))) int   i32x4;
typedef __attribute__((ext_vector_type(8))) int   i32x8;
typedef __attribute__((ext_vector_type(4))) float f32x4;

#define AS1 __attribute__((address_space(1)))
#define AS3 __attribute__((address_space(3)))

static __device__ inline void gload_lds16(const void* g, void* l) {
    __builtin_amdgcn_global_load_lds((const AS1 uint32_t*)g, (AS3 uint32_t*)l, 16, 0, 0);
}

static __device__ inline i32x8 cat8(i32x4 lo, i32x4 hi) {
    i32x8 r;
    r[0] = lo[0]; r[1] = lo[1]; r[2] = lo[2]; r[3] = lo[3];
    r[4] = hi[0]; r[5] = hi[1]; r[6] = hi[2]; r[7] = hi[3];
    return r;
}

// Native 2^x: arguments are |x| <= ~15, far from denormal/overflow edges.
static __device__ __forceinline__ float fexp2(float x) {
#if __has_builtin(__builtin_amdgcn_exp2f)
    return __builtin_amdgcn_exp2f(x);
#else
    float r;
    asm("v_exp_f32 %0, %1" : "=v"(r) : "v"(x));
    return r;
#endif
}

// Sum over the 16-lane DPP row on the VALU pipe. Result valid in lane 15.
static __device__ __forceinline__ float dpp_row_sum16(float v) {
    union { float f; int i; } u, s;
    u.f = v;
    s.i = __builtin_amdgcn_update_dpp(0, u.i, 0x118, 0xF, 0xF, true); u.f += s.f; // row_shr:8
    s.i = __builtin_amdgcn_update_dpp(0, u.i, 0x114, 0xF, 0xF, true); u.f += s.f; // row_shr:4
    s.i = __builtin_amdgcn_update_dpp(0, u.i, 0x112, 0xF, 0xF, true); u.f += s.f; // row_shr:2
    s.i = __builtin_amdgcn_update_dpp(0, u.i, 0x111, 0xF, 0xF, true); u.f += s.f; // row_shr:1
    return u.f;
}

// K1: L2-normalize rows of [x_i; x_j]; emit ONE fp8 e4m3 array
// z8 = fp8(z * SCALE_PRE). 2 rows per wave: lanes 0-31 -> row0, 32-63 ->
// row0+1; each lane loads float4 (16 B, wave = 1 KB contiguous) and stores
// 4 packed fp8 (u32, wave = 256 B contiguous). Rows never straddle the
// xi/xj boundary (8-row blocks, 4096 is 8-aligned). Also zeroes the
// row/col credit accumulators.
__global__ __launch_bounds__(256) void k_normalize(
        const float* __restrict__ xi, const float* __restrict__ xj,
        uint8_t* __restrict__ z8, float* __restrict__ rowacc,
        float* __restrict__ colacc, float* __restrict__ pos_acc,
        float* __restrict__ logsum, unsigned* __restrict__ done_ct) {
    const int wave = threadIdx.x >> 6;
    const int lane = threadIdx.x & 63;
    const int half = lane >> 5;          // 0/1: which of the wave's 2 rows
    const int il   = lane & 31;          // 32-lane index within the row
    const int row  = blockIdx.x * 8 + wave * 2 + half;
    const float* src = (row < 4096) ? (xi + (size_t)row * D_DIM)
                                    : (xj + (size_t)(row - 4096) * D_DIM);
    const float4 v = *(const float4*)(src + il * 4);
    float ss = (v.x * v.x + v.y * v.y) + (v.z * v.z + v.w * v.w);
#pragma unroll
    for (int m = 16; m >= 1; m >>= 1) ss += __shfl_xor(ss, m, 64);  // 32-lane half-reduce
    const float scale = SCALE_PRE / fmaxf(sqrtf(ss), L2EPS);
    int pk = __builtin_amdgcn_cvt_pk_fp8_f32(v.x * scale, v.y * scale, 0, false);
    pk = __builtin_amdgcn_cvt_pk_fp8_f32(v.z * scale, v.w * scale, pk, true);
    *(uint32_t*)(z8 + (size_t)row * D_DIM + il * 4) = (uint32_t)pk;

    if (blockIdx.x < 32)
        rowacc[blockIdx.x * 256 + threadIdx.x] = 0.0f;
    else if (blockIdx.x < 64)
        colacc[(blockIdx.x - 32) * 256 + threadIdx.x] = 0.0f;

    if (blockIdx.x == 0 && threadIdx.x == 0) {
        pos_acc[0] = 0.0f; logsum[0] = 0.0f; done_ct[0] = 0u;
    }
}

// K2 (4-distance circulant, 512-thread blocks): heavy bid<512: mb=bid>>6
// (0..7), b=bid&63. A = 256 rows: bands {b, b+1}, waves 0-3 own band b
// (32 rows each), waves 4-7 own band b+1. B = bands b1=b+4mb+2, b2=b+4mb+4
// staged in LDS (32 KB, XOR swizzle). Realized distances per block:
// b->b1=4mb+2, b->b2=4mb+4, (b+1)->b1=4mb+1, (b+1)->b2=4mb+3 -- over
// mb=0..7, b=0..63 this tiles distances 1..32 exactly once. d=32 (mb=7,
// waves<4, j>=8) is double-enumerated over b -> e*=0.5 + positives.
// Split-wait staging: b1 -> A -> b2, vmcnt(2)+barrier lets j<8 compute
// while b2 streams in.
// diag bid>=512: rb=bid-512, 128x128 strictly-upper, 8 waves x 16 rows.
// Credits -> rowacc/colacc via atomicAdd (no epilogue barriers).
__global__ __launch_bounds__(512) void k_gemm(
        const uint8_t* __restrict__ z8, float* __restrict__ rowacc,
        float* __restrict__ colacc, float* __restrict__ pos_acc) {
    __shared__ __align__(16) uint8_t lds[32768];   // 256 B-rows x 128 B fp8

    const int t = threadIdx.x;
    const int wave = t >> 6, lane = t & 63;
    const int quad = lane >> 4, lc = lane & 15;
    const int bid = blockIdx.x;

    const f32x4 z4 = {0.f, 0.f, 0.f, 0.f};

    if (bid < 512) {
        // ---------------- heavy path ----------------
        const int mb = bid >> 6;                 // 0..7
        const int b  = bid & 63;
        const int b1 = (b + 4 * mb + 2) & 63;
        const int b2 = (b + 4 * mb + 4) & 63;

        // Stage band b1 -> lds rows 0..127 (slots 0..1023, 2/thread).
#pragma unroll
        for (int q = 0; q < 2; q++) {
            const int s = q * 512 + t;
            const int r = s >> 3;                // 0..127
            const int g = (s & 7) ^ (r & 7);
            gload_lds16(z8 + (size_t)b1 * 128 * D_DIM + (size_t)r * D_DIM + g * 16,
                        &lds[s * 16]);
        }
        asm volatile("" ::: "memory");           // pin: b1 stages before A loads

        // A frags: wave w owns band (w<4 ? b : b+1), rows (w&3)*32 .. +31.
        const int ab = (wave < 4) ? b : ((b + 1) & 63);
        const int arow0 = ab * 128 + (wave & 3) * 32;
        i32x8 afr[2];
        {
            const uint8_t* pa = z8 + (size_t)(arow0 + lc) * D_DIM + quad * 32;
#pragma unroll
            for (int i = 0; i < 2; i++) {
                i32x4 lo = *(const i32x4*)(pa + i * 16 * D_DIM);
                i32x4 hi = *(const i32x4*)(pa + i * 16 * D_DIM + 16);
                afr[i] = cat8(lo, hi);
            }
        }
        asm volatile("" ::: "memory");           // pin: A loads before b2 stages

        // Stage band b2 -> lds rows 128..255 (slots 1024..2047).
#pragma unroll
        for (int q = 2; q < 4; q++) {
            const int s = q * 512 + t;
            const int r = s >> 3;                // 128..255
            const int g = (s & 7) ^ (r & 7);
            gload_lds16(z8 + (size_t)b2 * 128 * D_DIM + (size_t)(r - 128) * D_DIM + g * 16,
                        &lds[s * 16]);
        }

        // Wait b1 + A (leave b2's 2 loads in flight), then barrier.
        asm volatile("s_waitcnt vmcnt(2)" ::: "memory");
        __syncthreads();

        f32x4 rs4[2] = {z4, z4};
        float cs[16];
#pragma unroll
        for (int j = 0; j < 16; j++) cs[j] = 0.f;
        float posp = 0.f;

        // B-row jr = j*16+lc; jr&7 == lc&7 -> slot-units (quad*2..+1)^(lc&7).
#define MFMA_J(j, A0, A1)                                                     \
    i32x4 blo, bhi; {                                                         \
        const int rowb = ((j) * 16 + lc) * D_DIM;                             \
        blo = *(const i32x4*)&lds[rowb + (((quad * 2)     ^ (lc & 7)) * 16)]; \
        bhi = *(const i32x4*)&lds[rowb + (((quad * 2 + 1) ^ (lc & 7)) * 16)]; \
    }                                                                         \
    const i32x8 bfr = cat8(blo, bhi);                                         \
    f32x4 A0 = __builtin_amdgcn_mfma_scale_f32_16x16x128_f8f6f4(              \
                   afr[0], bfr, z4, 0, 0, 0, 131, 0, 127);                    \
    f32x4 A1 = __builtin_amdgcn_mfma_scale_f32_16x16x128_f8f6f4(              \
                   afr[1], bfr, z4, 0, 0, 0, 131, 0, 127);

#define CREDIT_FULL(j, A0, A1)                                                \
    {                                                                         \
        f32x4 ev0, ev1;                                                       \
        ev0[0] = fexp2(A0[0]); ev0[1] = fexp2(A0[1]);                         \
        ev0[2] = fexp2(A0[2]); ev0[3] = fexp2(A0[3]);                         \
        ev1[0] = fexp2(A1[0]); ev1[1] = fexp2(A1[1]);                         \
        ev1[2] = fexp2(A1[2]); ev1[3] = fexp2(A1[3]);                         \
        rs4[0] += ev0;                                                        \
        rs4[1] += ev1;                                                        \
        const f32x4 cv = ev0 + ev1;            /* packed: 2 v_pk_add_f32 */   \
        cs[j] += (cv[0] + cv[1]) + (cv[2] + cv[3]);                           \
    }

#pragma unroll
        for (int j = 0; j < 8; j++) {            // band b1: always full credit
            MFMA_J(j, a0, a1)
            CREDIT_FULL(j, a0, a1)
        }

        // Band b2 now resident.
        asm volatile("s_waitcnt vmcnt(0)" ::: "memory");
        __syncthreads();

        if (mb < 7) {                             // band b2: full credit
#pragma unroll
            for (int j = 8; j < 16; j++) {
                MFMA_J(j, a0, a1)
                CREDIT_FULL(j, a0, a1)
            }
        } else {
            // mb==7, j>=8: distance 32 for waves 0-3 (halve + positives);
            // distance 31 for waves 4-7 (full credit). Wave-uniform branch.
            if (wave < 4) {
#pragma unroll
                for (int j = 8; j < 16; j++) {
                    MFMA_J(j, a0, a1)
                    const int clb = (j - 8) * 16 + lc;   // band-local col
                    const int rl0 = wave * 32 + quad * 4;
#pragma unroll
                    for (int i = 0; i < 2; i++)
#pragma unroll
                        for (int r = 0; r < 4; r++) {
                            const float s = (i ? a1 : a0)[r];
                            const float e = 0.5f * fexp2(s);
                            if (clb == rl0 + i * 16 + r) posp += s;
                            rs4[i][r] += e;
                            cs[j] += e;
                        }
                }
            } else {
#pragma unroll
                for (int j = 8; j < 16; j++) {
                    MFMA_J(j, a0, a1)
                    CREDIT_FULL(j, a0, a1)
                }
            }
        }
#undef CREDIT_FULL
#undef MFMA_J

        // Row credits: DPP row-sum (lane 15 holds result) -> atomicAdd.
#pragma unroll
        for (int i = 0; i < 2; i++)
#pragma unroll
            for (int r = 0; r < 4; r++) {
                const float v = dpp_row_sum16(rs4[i][r]);
                if (lc == 15)
                    atomicAdd(&rowacc[arow0 + i * 16 + quad * 4 + r], v);
            }

        // Col credits: quad-reduce (2 shfl), quad 0 atomicAdds.
#pragma unroll
        for (int j = 0; j < 16; j++) {
            cs[j] += __shfl_xor(cs[j], 16, 64);
            cs[j] += __shfl_xor(cs[j], 32, 64);
        }
        if (quad == 0) {
#pragma unroll
            for (int j = 0; j < 16; j++) {
                const int band = (j < 8) ? b1 : b2;
                atomicAdd(&colacc[band * 128 + (j & 7) * 16 + lc], cs[j]);
            }
        }

        if (mb == 7 && wave < 4) {
#pragma unroll
            for (int mm = 32; mm >= 1; mm >>= 1) posp += __shfl_xor(posp, mm, 64);
            if (lane == 0) atomicAdd(pos_acc, posp);
        }
        return;
    }

    // ---------------- diag path: 128x128 strictly-upper, 8 waves x 16 rows --
    const int rb = bid - 512;
    {
        const uint8_t* zb = z8 + (size_t)rb * 128 * D_DIM;
#pragma unroll
        for (int q = 0; q < 2; q++) {
            const int s = q * 512 + t;           // 0..1023
            const int r = s >> 3;                // 0..127
            const int g = (s & 7) ^ (r & 7);
            gload_lds16(zb + (size_t)r * D_DIM + g * 16, &lds[s * 16]);
        }
    }

    i32x8 afr;
    {
        const uint8_t* pa = z8 + (size_t)(rb * 128 + wave * 16 + lc) * D_DIM + quad * 32;
        i32x4 lo = *(const i32x4*)pa;
        i32x4 hi = *(const i32x4*)(pa + 16);
        afr = cat8(lo, hi);
    }

    asm volatile("s_waitcnt vmcnt(0)" ::: "memory");
    __syncthreads();

    f32x4 rs4 = z4;
    float cs[8];
#pragma unroll
    for (int j = 0; j < 8; j++) cs[j] = 0.f;
    const int rl0 = wave * 16 + quad * 4;        // local row = rl0 + r

#pragma unroll
    for (int j = 0; j < 8; j++) {
        i32x4 blo, bhi; {
            const int rowb = (j * 16 + lc) * D_DIM;
            blo = *(const i32x4*)&lds[rowb + (((quad * 2)     ^ (lc & 7)) * 16)];
            bhi = *(const i32x4*)&lds[rowb + (((quad * 2 + 1) ^ (lc & 7)) * 16)];
        }
        const i32x8 bfr = cat8(blo, bhi);
        f32x4 a0 = __builtin_amdgcn_mfma_scale_f32_16x16x128_f8f6f4(
                       afr, bfr, z4, 0, 0, 0, 131, 0, 127);
        const int cl = j * 16 + lc;
#pragma unroll
        for (int r = 0; r < 4; r++) {
            const float e = (cl > rl0 + r) ? fexp2(a0[r]) : 0.f;
            rs4[r] += e;
            cs[j] += e;
        }
    }

#pragma unroll
    for (int r = 0; r < 4; r++) {
        const float v = dpp_row_sum16(rs4[r]);
        if (lc == 15)
            atomicAdd(&rowacc[rb * 128 + rl0 + r], v);
    }

#pragma unroll
    for (int j = 0; j < 8; j++) {
        cs[j] += __shfl_xor(cs[j], 16, 64);
        cs[j] += __shfl_xor(cs[j], 32, 64);
    }
    if (quad == 0) {
#pragma unroll
        for (int j = 0; j < 8; j++)
            atomicAdd(&colacc[rb * 128 + j * 16 + lc], cs[j]);
    }
}

// K3 (fused logsum + combine): 32 blocks, one row per thread; last block
// writes the final loss. Denominator = rowacc + colacc.
__global__ __launch_bounds__(256) void k_logsum(
        const float* __restrict__ rowacc, const float* __restrict__ colacc,
        float* __restrict__ pos_acc, float* __restrict__ logsum,
        unsigned* __restrict__ done_ct, float* __restrict__ out) {
    const int row = blockIdx.x * 256 + threadIdx.x;
    const float d = rowacc[row] + colacc[row];
    float v = __logf(d);
#pragma unroll
    for (int m = 32; m >= 1; m >>= 1) v += __shfl_xor(v, m, 64);
    if ((threadIdx.x & 63) == 0) atomicAdd(logsum, v);
    __threadfence();
    __syncthreads();
    if (threadIdx.x == 0) {
        const unsigned prev = atomicAdd(done_ct, 1u);
        if (prev == gridDim.x - 1) {
            __threadfence();
            const float ls = atomicAdd(logsum, 0.0f);
            const float pp = atomicAdd(pos_acc, 0.0f);
            out[0] = (ls - pp * LN2) / (float)NROW;
        }
    }
}

extern "C" void kernel_launch(void* const* d_in, const int* in_sizes, int n_in,
                              void* d_out, int out_size, void* d_ws, size_t ws_size,
                              hipStream_t stream) {
    const float* xi = (const float*)d_in[0];
    const float* xj = (const float*)d_in[1];
    uint8_t* z8 = (uint8_t*)d_ws;                                // 1 MB fp8
    float* rowacc = (float*)(z8 + (size_t)NROW * D_DIM);         // 8192 f32
    float* colacc = rowacc + NROW;                               // 8192 f32
    float* pos_acc = colacc + NROW;
    float* logsum = pos_acc + 1;
    unsigned* done_ct = (unsigned*)(logsum + 1);
    float* out = (float*)d_out;

    hipLaunchKernelGGL(k_normalize, dim3(NROW / 8), dim3(256), 0, stream,
                       xi, xj, z8, rowacc, colacc, pos_acc, logsum, done_ct);
    hipLaunchKernelGGL(k_gemm, dim3(512 + 64), dim3(512), 0, stream,
                       z8, rowacc, colacc, pos_acc);
    hipLaunchKernelGGL(k_logsum, dim3(NROW / 256), dim3(256), 0, stream,
                       rowacc, colacc, pos_acc, logsum, done_ct, out);
}

// Round 8
// 75.133 us; speedup vs baseline: 1.0401x; 1.0401x over previous
//
#include <hip/hip_runtime.h>
#include <stdint.h>

#define D_DIM 128
#define NROW 8192          // 2B
#define L2EPS 1e-12f
// MFMA output = sim * 10/ln2 (exp2 arg): data pre-scaled by sqrt((10/ln2)/16),
// MX scales A=2^4 (131), B=2^0 (127).
#define SCALE_PRE 0.9495707f
#define LN2 0.6931471805599453f

typedef __attribute__((ext_vector_type(4))) int   i32x4;
typedef __attribute__((ext_vector_type(8))) int   i32x8;
typedef __attribute__((ext_vector_type(4))) float f32x4;

#define AS1 __attribute__((address_space(1)))
#define AS3 __attribute__((address_space(3)))

static __device__ inline void gload_lds16(const void* g, void* l) {
    __builtin_amdgcn_global_load_lds((const AS1 uint32_t*)g, (AS3 uint32_t*)l, 16, 0, 0);
}

static __device__ inline i32x8 cat8(i32x4 lo, i32x4 hi) {
    i32x8 r;
    r[0] = lo[0]; r[1] = lo[1]; r[2] = lo[2]; r[3] = lo[3];
    r[4] = hi[0]; r[5] = hi[1]; r[6] = hi[2]; r[7] = hi[3];
    return r;
}

// Native 2^x: arguments are |x| <= ~15, far from denormal/overflow edges.
static __device__ __forceinline__ float fexp2(float x) {
#if __has_builtin(__builtin_amdgcn_exp2f)
    return __builtin_amdgcn_exp2f(x);
#else
    float r;
    asm("v_exp_f32 %0, %1" : "=v"(r) : "v"(x));
    return r;
#endif
}

// Sum over the 16-lane DPP row on the VALU pipe. Result valid in lane 15.
static __device__ __forceinline__ float dpp_row_sum16(float v) {
    union { float f; int i; } u, s;
    u.f = v;
    s.i = __builtin_amdgcn_update_dpp(0, u.i, 0x118, 0xF, 0xF, true); u.f += s.f; // row_shr:8
    s.i = __builtin_amdgcn_update_dpp(0, u.i, 0x114, 0xF, 0xF, true); u.f += s.f; // row_shr:4
    s.i = __builtin_amdgcn_update_dpp(0, u.i, 0x112, 0xF, 0xF, true); u.f += s.f; // row_shr:2
    s.i = __builtin_amdgcn_update_dpp(0, u.i, 0x111, 0xF, 0xF, true); u.f += s.f; // row_shr:1
    return u.f;
}

// K1: L2-normalize rows of [x_i; x_j]; emit ONE fp8 e4m3 array
// z8 = fp8(z * SCALE_PRE). Also zeroes the row/col credit accumulators.
__global__ __launch_bounds__(256) void k_normalize(
        const float* __restrict__ xi, const float* __restrict__ xj,
        uint8_t* __restrict__ z8, float* __restrict__ rowacc,
        float* __restrict__ colacc, float* __restrict__ pos_acc,
        float* __restrict__ logsum, unsigned* __restrict__ done_ct) {
    const int wave = threadIdx.x >> 6;
    const int lane = threadIdx.x & 63;
    const int row = blockIdx.x * 4 + wave;
    const float* src = (row < 4096) ? (xi + (size_t)row * D_DIM)
                                    : (xj + (size_t)(row - 4096) * D_DIM);
    float2 v = *(const float2*)(src + lane * 2);
    float ss = v.x * v.x + v.y * v.y;
#pragma unroll
    for (int m = 32; m >= 1; m >>= 1) ss += __shfl_xor(ss, m, 64);
    const float scale = SCALE_PRE / fmaxf(sqrtf(ss), L2EPS);
    const int pk = __builtin_amdgcn_cvt_pk_fp8_f32(v.x * scale, v.y * scale, 0, false);
    *(ushort*)(z8 + (size_t)row * D_DIM + lane * 2) = (ushort)pk;

    if (blockIdx.x < 32)
        rowacc[blockIdx.x * 256 + threadIdx.x] = 0.0f;
    else if (blockIdx.x < 64)
        colacc[(blockIdx.x - 32) * 256 + threadIdx.x] = 0.0f;

    if (blockIdx.x == 0 && threadIdx.x == 0) {
        pos_acc[0] = 0.0f; logsum[0] = 0.0f; done_ct[0] = 0u;
    }
}

// K2 (4-distance circulant, 512-thread blocks): heavy bid<512: mb=bid>>6
// (0..7), b=bid&63. A = 256 rows: bands {b, b+1}, waves 0-3 own band b
// (32 rows each), waves 4-7 own band b+1. B = bands b1=b+4mb+2, b2=b+4mb+4
// staged in LDS (32 KB, XOR swizzle). Realized distances per block:
// b->b1=4mb+2, b->b2=4mb+4, (b+1)->b1=4mb+1, (b+1)->b2=4mb+3 -- over
// mb=0..7, b=0..63 this tiles distances 1..32 exactly once. d=32 (mb=7,
// waves<4, j>=8) is double-enumerated over b -> e*=0.5 + positives.
// Split-wait staging: b1 -> A -> b2, vmcnt(2)+barrier lets j<8 compute
// while b2 streams in.
// diag bid>=512: rb=bid-512, 128x128 strictly-upper, 8 waves x 16 rows.
// Credits -> rowacc/colacc via atomicAdd (no epilogue barriers).
__global__ __launch_bounds__(512) void k_gemm(
        const uint8_t* __restrict__ z8, float* __restrict__ rowacc,
        float* __restrict__ colacc, float* __restrict__ pos_acc) {
    __shared__ __align__(16) uint8_t lds[32768];   // 256 B-rows x 128 B fp8

    const int t = threadIdx.x;
    const int wave = t >> 6, lane = t & 63;
    const int quad = lane >> 4, lc = lane & 15;
    const int bid = blockIdx.x;

    const f32x4 z4 = {0.f, 0.f, 0.f, 0.f};

    if (bid < 512) {
        // ---------------- heavy path ----------------
        const int mb = bid >> 6;                 // 0..7
        const int b  = bid & 63;
        const int b1 = (b + 4 * mb + 2) & 63;
        const int b2 = (b + 4 * mb + 4) & 63;

        // Stage band b1 -> lds rows 0..127 (slots 0..1023, 2/thread).
#pragma unroll
        for (int q = 0; q < 2; q++) {
            const int s = q * 512 + t;
            const int r = s >> 3;                // 0..127
            const int g = (s & 7) ^ (r & 7);
            gload_lds16(z8 + (size_t)b1 * 128 * D_DIM + (size_t)r * D_DIM + g * 16,
                        &lds[s * 16]);
        }
        asm volatile("" ::: "memory");           // pin: b1 stages before A loads

        // A frags: wave w owns band (w<4 ? b : b+1), rows (w&3)*32 .. +31.
        const int ab = (wave < 4) ? b : ((b + 1) & 63);
        const int arow0 = ab * 128 + (wave & 3) * 32;
        i32x8 afr[2];
        {
            const uint8_t* pa = z8 + (size_t)(arow0 + lc) * D_DIM + quad * 32;
#pragma unroll
            for (int i = 0; i < 2; i++) {
                i32x4 lo = *(const i32x4*)(pa + i * 16 * D_DIM);
                i32x4 hi = *(const i32x4*)(pa + i * 16 * D_DIM + 16);
                afr[i] = cat8(lo, hi);
            }
        }
        asm volatile("" ::: "memory");           // pin: A loads before b2 stages

        // Stage band b2 -> lds rows 128..255 (slots 1024..2047).
#pragma unroll
        for (int q = 2; q < 4; q++) {
            const int s = q * 512 + t;
            const int r = s >> 3;                // 128..255
            const int g = (s & 7) ^ (r & 7);
            gload_lds16(z8 + (size_t)b2 * 128 * D_DIM + (size_t)(r - 128) * D_DIM + g * 16,
                        &lds[s * 16]);
        }

        // Wait b1 + A (leave b2's 2 loads in flight), then barrier.
        asm volatile("s_waitcnt vmcnt(2)" ::: "memory");
        __syncthreads();

        f32x4 rs4[2] = {z4, z4};
        float cs[16];
#pragma unroll
        for (int j = 0; j < 16; j++) cs[j] = 0.f;
        float posp = 0.f;

        // B-row jr = j*16+lc; jr&7 == lc&7 -> slot-units (quad*2..+1)^(lc&7).
#define MFMA_J(j, A0, A1)                                                     \
    i32x4 blo, bhi; {                                                         \
        const int rowb = ((j) * 16 + lc) * D_DIM;                             \
        blo = *(const i32x4*)&lds[rowb + (((quad * 2)     ^ (lc & 7)) * 16)]; \
        bhi = *(const i32x4*)&lds[rowb + (((quad * 2 + 1) ^ (lc & 7)) * 16)]; \
    }                                                                         \
    const i32x8 bfr = cat8(blo, bhi);                                         \
    f32x4 A0 = __builtin_amdgcn_mfma_scale_f32_16x16x128_f8f6f4(              \
                   afr[0], bfr, z4, 0, 0, 0, 131, 0, 127);                    \
    f32x4 A1 = __builtin_amdgcn_mfma_scale_f32_16x16x128_f8f6f4(              \
                   afr[1], bfr, z4, 0, 0, 0, 131, 0, 127);

#define CREDIT_FULL(j, A0, A1)                                                \
    {                                                                         \
        f32x4 ev0, ev1;                                                       \
        ev0[0] = fexp2(A0[0]); ev0[1] = fexp2(A0[1]);                         \
        ev0[2] = fexp2(A0[2]); ev0[3] = fexp2(A0[3]);                         \
        ev1[0] = fexp2(A1[0]); ev1[1] = fexp2(A1[1]);                         \
        ev1[2] = fexp2(A1[2]); ev1[3] = fexp2(A1[3]);                         \
        rs4[0] += ev0;                                                        \
        rs4[1] += ev1;                                                        \
        cs[j] += ((ev0[0] + ev0[1]) + (ev0[2] + ev0[3]))                      \
               + ((ev1[0] + ev1[1]) + (ev1[2] + ev1[3]));                     \
    }

#pragma unroll
        for (int j = 0; j < 8; j++) {            // band b1: always full credit
            MFMA_J(j, a0, a1)
            CREDIT_FULL(j, a0, a1)
        }

        // Band b2 now resident.
        asm volatile("s_waitcnt vmcnt(0)" ::: "memory");
        __syncthreads();

        if (mb < 7) {                             // band b2: full credit
#pragma unroll
            for (int j = 8; j < 16; j++) {
                MFMA_J(j, a0, a1)
                CREDIT_FULL(j, a0, a1)
            }
        } else {
            // mb==7, j>=8: distance 32 for waves 0-3 (halve + positives);
            // distance 31 for waves 4-7 (full credit). Wave-uniform branch.
            if (wave < 4) {
#pragma unroll
                for (int j = 8; j < 16; j++) {
                    MFMA_J(j, a0, a1)
                    const int clb = (j - 8) * 16 + lc;   // band-local col
                    const int rl0 = wave * 32 + quad * 4;
#pragma unroll
                    for (int i = 0; i < 2; i++)
#pragma unroll
                        for (int r = 0; r < 4; r++) {
                            const float s = (i ? a1 : a0)[r];
                            const float e = 0.5f * fexp2(s);
                            if (clb == rl0 + i * 16 + r) posp += s;
                            rs4[i][r] += e;
                            cs[j] += e;
                        }
                }
            } else {
#pragma unroll
                for (int j = 8; j < 16; j++) {
                    MFMA_J(j, a0, a1)
                    CREDIT_FULL(j, a0, a1)
                }
            }
        }
#undef CREDIT_FULL
#undef MFMA_J

        // Row credits: DPP row-sum (lane 15 holds result) -> atomicAdd.
#pragma unroll
        for (int i = 0; i < 2; i++)
#pragma unroll
            for (int r = 0; r < 4; r++) {
                const float v = dpp_row_sum16(rs4[i][r]);
                if (lc == 15)
                    atomicAdd(&rowacc[arow0 + i * 16 + quad * 4 + r], v);
            }

        // Col credits: quad-reduce (2 shfl), quad 0 atomicAdds.
#pragma unroll
        for (int j = 0; j < 16; j++) {
            cs[j] += __shfl_xor(cs[j], 16, 64);
            cs[j] += __shfl_xor(cs[j], 32, 64);
        }
        if (quad == 0) {
#pragma unroll
            for (int j = 0; j < 16; j++) {
                const int band = (j < 8) ? b1 : b2;
                atomicAdd(&colacc[band * 128 + (j & 7) * 16 + lc], cs[j]);
            }
        }

        if (mb == 7 && wave < 4) {
#pragma unroll
            for (int mm = 32; mm >= 1; mm >>= 1) posp += __shfl_xor(posp, mm, 64);
            if (lane == 0) atomicAdd(pos_acc, posp);
        }
        return;
    }

    // ---------------- diag path: 128x128 strictly-upper, 8 waves x 16 rows --
    const int rb = bid - 512;
    {
        const uint8_t* zb = z8 + (size_t)rb * 128 * D_DIM;
#pragma unroll
        for (int q = 0; q < 2; q++) {
            const int s = q * 512 + t;           // 0..1023
            const int r = s >> 3;                // 0..127
            const int g = (s & 7) ^ (r & 7);
            gload_lds16(zb + (size_t)r * D_DIM + g * 16, &lds[s * 16]);
        }
    }

    i32x8 afr;
    {
        const uint8_t* pa = z8 + (size_t)(rb * 128 + wave * 16 + lc) * D_DIM + quad * 32;
        i32x4 lo = *(const i32x4*)pa;
        i32x4 hi = *(const i32x4*)(pa + 16);
        afr = cat8(lo, hi);
    }

    asm volatile("s_waitcnt vmcnt(0)" ::: "memory");
    __syncthreads();

    f32x4 rs4 = z4;
    float cs[8];
#pragma unroll
    for (int j = 0; j < 8; j++) cs[j] = 0.f;
    const int rl0 = wave * 16 + quad * 4;        // local row = rl0 + r

#pragma unroll
    for (int j = 0; j < 8; j++) {
        i32x4 blo, bhi; {
            const int rowb = (j * 16 + lc) * D_DIM;
            blo = *(const i32x4*)&lds[rowb + (((quad * 2)     ^ (lc & 7)) * 16)];
            bhi = *(const i32x4*)&lds[rowb + (((quad * 2 + 1) ^ (lc & 7)) * 16)];
        }
        const i32x8 bfr = cat8(blo, bhi);
        f32x4 a0 = __builtin_amdgcn_mfma_scale_f32_16x16x128_f8f6f4(
                       afr, bfr, z4, 0, 0, 0, 131, 0, 127);
        const int cl = j * 16 + lc;
#pragma unroll
        for (int r = 0; r < 4; r++) {
            const float e = (cl > rl0 + r) ? fexp2(a0[r]) : 0.f;
            rs4[r] += e;
            cs[j] += e;
        }
    }

#pragma unroll
    for (int r = 0; r < 4; r++) {
        const float v = dpp_row_sum16(rs4[r]);
        if (lc == 15)
            atomicAdd(&rowacc[rb * 128 + rl0 + r], v);
    }

#pragma unroll
    for (int j = 0; j < 8; j++) {
        cs[j] += __shfl_xor(cs[j], 16, 64);
        cs[j] += __shfl_xor(cs[j], 32, 64);
    }
    if (quad == 0) {
#pragma unroll
        for (int j = 0; j < 8; j++)
            atomicAdd(&colacc[rb * 128 + j * 16 + lc], cs[j]);
    }
}

// K3 (fused logsum + combine): 32 blocks, one row per thread; last block
// writes the final loss. Denominator = rowacc + colacc.
__global__ __launch_bounds__(256) void k_logsum(
        const float* __restrict__ rowacc, const float* __restrict__ colacc,
        float* __restrict__ pos_acc, float* __restrict__ logsum,
        unsigned* __restrict__ done_ct, float* __restrict__ out) {
    const int row = blockIdx.x * 256 + threadIdx.x;
    const float d = rowacc[row] + colacc[row];
    float v = __logf(d);
#pragma unroll
    for (int m = 32; m >= 1; m >>= 1) v += __shfl_xor(v, m, 64);
    if ((threadIdx.x & 63) == 0) atomicAdd(logsum, v);
    __threadfence();
    __syncthreads();
    if (threadIdx.x == 0) {
        const unsigned prev = atomicAdd(done_ct, 1u);
        if (prev == gridDim.x - 1) {
            __threadfence();
            const float ls = atomicAdd(logsum, 0.0f);
            const float pp = atomicAdd(pos_acc, 0.0f);
            out[0] = (ls - pp * LN2) / (float)NROW;
        }
    }
}

extern "C" void kernel_launch(void* const* d_in, const int* in_sizes, int n_in,
                              void* d_out, int out_size, void* d_ws, size_t ws_size,
                              hipStream_t stream) {
    const float* xi = (const float*)d_in[0];
    const float* xj = (const float*)d_in[1];
    uint8_t* z8 = (uint8_t*)d_ws;                                // 1 MB fp8
    float* rowacc = (float*)(z8 + (size_t)NROW * D_DIM);         // 8192 f32
    float* colacc = rowacc + NROW;                               // 8192 f32
    float* pos_acc = colacc + NROW;
    float* logsum = pos_acc + 1;
    unsigned* done_ct = (unsigned*)(logsum + 1);
    float* out = (float*)d_out;

    hipLaunchKernelGGL(k_normalize, dim3(NROW / 4), dim3(256), 0, stream,
                       xi, xj, z8, rowacc, colacc, pos_acc, logsum, done_ct);
    hipLaunchKernelGGL(k_gemm, dim3(512 + 64), dim3(512), 0, stream,
                       z8, rowacc, colacc, pos_acc);
    hipLaunchKernelGGL(k_logsum, dim3(NROW / 256), dim3(256), 0, stream,
                       rowacc, colacc, pos_acc, logsum, done_ct, out);
}